// Round 4
// baseline (454.289 us; speedup 1.0000x reference)
//
#include <hip/hip_runtime.h>

typedef unsigned short u16;
typedef __attribute__((ext_vector_type(8))) __bf16 bf16x8;
typedef __attribute__((ext_vector_type(4))) __bf16 bf16x4;
typedef __attribute__((ext_vector_type(4))) float f32x4;
typedef __attribute__((ext_vector_type(4))) unsigned short u16x4;

#define AS1 __attribute__((address_space(1)))
#define AS3 __attribute__((address_space(3)))

__device__ __forceinline__ void async_load16(const void* g, void* l) {
  __builtin_amdgcn_global_load_lds((const AS1 void*)g, (AS3 void*)l, 16, 0, 0);
}

__device__ __forceinline__ float exp2_fast(float x) {
#if __has_builtin(__builtin_amdgcn_exp2f)
  return __builtin_amdgcn_exp2f(x);
#else
  return exp2f(x);
#endif
}
__device__ __forceinline__ float rcp_fast(float x) {
#if __has_builtin(__builtin_amdgcn_rcpf)
  return __builtin_amdgcn_rcpf(x);
#else
  return 1.0f / x;
#endif
}

__device__ __forceinline__ u16 f2bf(float f) {   // manual RNE
  union { float f; unsigned u; } a; a.f = f;
  unsigned u = a.u;
  u += 0x7fffu + ((u >> 16) & 1u);
  return (u16)(u >> 16);
}
__device__ __forceinline__ u16 bf_bits(float f) {  // native cvt (RNE)
  union { __bf16 b; u16 u; } c; c.b = (__bf16)f; return c.u;
}
__device__ __forceinline__ float bf2f(u16 h) {
  union { unsigned u; float f; } c; c.u = ((unsigned)h) << 16; return c.f;
}

// ------- fp32 -> bf16: all 6 weights in ONE launch (dst contiguous in ws) -------
__global__ __launch_bounds__(256)
void f2b_all(const float* __restrict__ s0, const float* __restrict__ s1,
             const float* __restrict__ s2, const float* __restrict__ s3,
             const float* __restrict__ s4, const float* __restrict__ s5,
             u16* __restrict__ dst) {
  const int i = blockIdx.x * 256 + threadIdx.x;   // < 3145728
  const float* s; int off;
  if (i < 1048576) {
    if (i < 262144)      { s = s0; off = i; }
    else if (i < 524288) { s = s1; off = i - 262144; }
    else if (i < 786432) { s = s2; off = i - 524288; }
    else                 { s = s3; off = i - 786432; }
  } else if (i < 2097152) { s = s4; off = i - 1048576; }
  else                    { s = s5; off = i - 2097152; }
  const float4 v = ((const float4*)s)[off];
  u16x4 o; o[0] = f2bf(v.x); o[1] = f2bf(v.y); o[2] = f2bf(v.z); o[3] = f2bf(v.w);
  ((u16x4*)dst)[i] = o;
}

// ---------------- LayerNorm (1024 cols, 1 block/row) ----------------
__global__ __launch_bounds__(256)
void ln_kernel(const float* __restrict__ x, const float* __restrict__ g,
               const float* __restrict__ b, u16* __restrict__ out) {
  const int row = blockIdx.x, tid = threadIdx.x;
  const float4 v = ((const float4*)(x + (size_t)row * 1024))[tid];
  float s = v.x + v.y + v.z + v.w;
  float s2 = v.x * v.x + v.y * v.y + v.z * v.z + v.w * v.w;
#pragma unroll
  for (int o = 1; o < 64; o <<= 1) { s += __shfl_xor(s, o); s2 += __shfl_xor(s2, o); }
  __shared__ float red[8];
  const int wave = tid >> 6, lane = tid & 63;
  if (lane == 0) { red[wave] = s; red[wave + 4] = s2; }
  __syncthreads();
  s = red[0] + red[1] + red[2] + red[3];
  s2 = red[4] + red[5] + red[6] + red[7];
  const float mu = s * (1.f / 1024.f);
  const float rstd = rsqrtf(s2 * (1.f / 1024.f) - mu * mu + 1e-5f);
  const float4 gg = ((const float4*)g)[tid];
  const float4 bb = ((const float4*)b)[tid];
  u16x4 o4;
  o4[0] = f2bf((v.x - mu) * rstd * gg.x + bb.x);
  o4[1] = f2bf((v.y - mu) * rstd * gg.y + bb.y);
  o4[2] = f2bf((v.z - mu) * rstd * gg.z + bb.z);
  o4[3] = f2bf((v.w - mu) * rstd * gg.w + bb.w);
  ((u16x4*)(out + (size_t)row * 1024))[tid] = o4;
}

// -- fused: out = x + p[0..3] + bo (bf16 partials); hb = LN(out; g,b) --
__global__ __launch_bounds__(256)
void ln_fuse(const float* __restrict__ x, const u16* __restrict__ parts,
             const float* __restrict__ bo, const float* __restrict__ g,
             const float* __restrict__ b, float* __restrict__ out,
             u16* __restrict__ hb) {
  const int row = blockIdx.x, tid = threadIdx.x;
  const size_t base = (size_t)row * 1024;
  const int i4 = row * 256 + tid;
  const float4 xv = ((const float4*)(x + base))[tid];
  const float4 bv = ((const float4*)bo)[tid];
  float4 t;
  t.x = xv.x + bv.x; t.y = xv.y + bv.y; t.z = xv.z + bv.z; t.w = xv.w + bv.w;
#pragma unroll
  for (int kz = 0; kz < 4; kz++) {
    const u16x4 h = ((const u16x4*)(parts + (size_t)kz * 4194304))[i4];
    t.x += bf2f(h[0]); t.y += bf2f(h[1]); t.z += bf2f(h[2]); t.w += bf2f(h[3]);
  }
  ((float4*)(out + base))[tid] = t;
  float s = t.x + t.y + t.z + t.w;
  float s2 = t.x * t.x + t.y * t.y + t.z * t.z + t.w * t.w;
#pragma unroll
  for (int o = 1; o < 64; o <<= 1) { s += __shfl_xor(s, o); s2 += __shfl_xor(s2, o); }
  __shared__ float red[8];
  const int wave = tid >> 6, lane = tid & 63;
  if (lane == 0) { red[wave] = s; red[wave + 4] = s2; }
  __syncthreads();
  s = red[0] + red[1] + red[2] + red[3];
  s2 = red[4] + red[5] + red[6] + red[7];
  const float mu = s * (1.f / 1024.f);
  const float rstd = rsqrtf(s2 * (1.f / 1024.f) - mu * mu + 1e-5f);
  const float4 gg = ((const float4*)g)[tid];
  const float4 bb = ((const float4*)b)[tid];
  u16x4 o4;
  o4[0] = f2bf((t.x - mu) * rstd * gg.x + bb.x);
  o4[1] = f2bf((t.y - mu) * rstd * gg.y + bb.y);
  o4[2] = f2bf((t.z - mu) * rstd * gg.z + bb.z);
  o4[3] = f2bf((t.w - mu) * rstd * gg.w + bb.w);
  ((u16x4*)(hb + base))[tid] = o4;
}

// ------- out += p[0..3] + b2 (MLP2 reduction over 4 bf16 partial slices) -------
__global__ __launch_bounds__(256)
void add4(float* __restrict__ out, const u16* __restrict__ p,
          const float* __restrict__ b2) {
  const int i = blockIdx.x * 256 + threadIdx.x;   // f4 index < 1048576
  const float4 o = ((const float4*)out)[i];
  const float4 bv = ((const float4*)b2)[i & 255];
  float a0 = o.x + bv.x, a1 = o.y + bv.y, a2 = o.z + bv.z, a3 = o.w + bv.w;
#pragma unroll
  for (int kz = 0; kz < 4; kz++) {
    const u16x4 h = ((const u16x4*)(p + (size_t)kz * 4194304))[i];
    a0 += bf2f(h[0]); a1 += bf2f(h[1]); a2 += bf2f(h[2]); a3 += bf2f(h[3]);
  }
  float4 r; r.x = a0; r.y = a1; r.z = a2; r.w = a3;
  ((float4*)out)[i] = r;
}

// ============ 8-phase 256x256 GEMM (T2+T3+T4+T5), C = A * B^T ============
// A[M,ldk] bf16, B[N,ldk] bf16. BM=BN=256, BK=64, 512 thr (8 waves, 2Mx4N),
// LDS 128KB = 2 dbuf x (A 2x[128][64] + B 2x[128][64]) bf16, st_16x32 swizzle
// applied via pre-swizzled global source (LDS dest linear+WAVE-UNIFORM for
// global_load_lds, per m104/m108) + swizzled ds_read. Counted vmcnt(4) at
// phases 4/8 only (vmcnt(0) on peeled last iter).
// __launch_bounds__(512) with NO min-occupancy arg: R3's (512,2) capped VGPR
// at 128 < the ~230 this kernel needs -> scratch spills (90MB WRITE_SIZE).
// Barriers are asm-with-memory-clobber so they are also compiler fences for
// ds/vmem ops; exactly ONE sched_barrier(0) per phase (rule 18, MFMA-vs-lgkm).
template <class Epi>
__global__ __launch_bounds__(512)
void gemm8(const u16* __restrict__ A, const u16* __restrict__ Bw,
           int ldk, int K, int NB, Epi epi) {
  __shared__ __align__(16) u16 lds[65536];   // A: [buf][half][8192] @0 ; B @32768
  const int tid = threadIdx.x;
  const int lane = tid & 63, wave = tid >> 6;
  const int quad = lane >> 4, l16 = lane & 15;
  const int wmh = wave >> 2, wn = wave & 3;
  const int id = blockIdx.x;
  const int mb = id & 15;
  const int t = id >> 4;
  const int nb = t % NB;
  const int kz = t / NB;
  const int bm = mb * 256, bn = nb * 256;
  const int ntile = K >> 6;
  const int iters = ntile >> 1;

  // ---- staging source coords (inverse-swizzled global source; per-lane OK) ----
  const int srow = tid >> 3;
  const int scol = ((tid & 7) * 8) ^ (((tid >> 5) & 1) << 4);
  const size_t ldkz = (size_t)ldk;
  const u16* Ag = A + (size_t)(bm + srow) * ldkz + (size_t)kz * K + scol;
  const u16* Bg = Bw + (size_t)(bn + srow) * ldkz + (size_t)kz * K + scol;

  // LDS dest: wave-uniform base; HW places lane i at base + i*16B (m104/m108).
#define STAGE(kt, hf) do { \
    const u16* gp_ = (((hf) & 2) ? Bg : Ag) + (size_t)(((hf) & 1) * 128) * ldkz + (size_t)(kt) * 64; \
    u16* lp_ = &lds[(((hf) & 2) ? 32768 : 0) + (((kt) & 1) * 2 + ((hf) & 1)) * 8192 + wave * 512]; \
    async_load16(gp_, lp_); \
    async_load16(gp_ + 64 * ldkz, lp_ + 4096); \
  } while (0)
#define STG(kt, hf) do { if ((kt) >= 2 && (kt) < ntile) STAGE(kt, hf); } while (0)

  // ---- fragment read offsets (swizzled) ----
  const int qsw = (quad ^ (2 * ((l16 >> 2) & 1))) * 8;
  const int fro = l16 * 64 + qsw;
  const u16* aB0 = &lds[(0 * 2 + wmh) * 8192];
  const u16* aB1 = &lds[(1 * 2 + wmh) * 8192];
  const u16* bB0 = &lds[32768 + (0 * 2 + (wn >> 1)) * 8192 + (wn & 1) * 4096];
  const u16* bB1 = &lds[32768 + (1 * 2 + (wn >> 1)) * 8192 + (wn & 1) * 4096];

  bf16x8 aF[4][2], bF[4][2];
  const f32x4 fz = {0.f, 0.f, 0.f, 0.f};
  f32x4 acc[8][4];
#pragma unroll
  for (int m = 0; m < 8; m++)
#pragma unroll
    for (int n = 0; n < 4; n++) acc[m][n] = fz;

#define LDAH(ab, mq) do { \
    aF[0][0] = *(const bf16x8*)&(ab)[fro + ((mq)*4 + 0) * 1024];      \
    aF[0][1] = *(const bf16x8*)&(ab)[fro + ((mq)*4 + 0) * 1024 + 32]; \
    aF[1][0] = *(const bf16x8*)&(ab)[fro + ((mq)*4 + 1) * 1024];      \
    aF[1][1] = *(const bf16x8*)&(ab)[fro + ((mq)*4 + 1) * 1024 + 32]; \
    aF[2][0] = *(const bf16x8*)&(ab)[fro + ((mq)*4 + 2) * 1024];      \
    aF[2][1] = *(const bf16x8*)&(ab)[fro + ((mq)*4 + 2) * 1024 + 32]; \
    aF[3][0] = *(const bf16x8*)&(ab)[fro + ((mq)*4 + 3) * 1024];      \
    aF[3][1] = *(const bf16x8*)&(ab)[fro + ((mq)*4 + 3) * 1024 + 32]; \
  } while (0)
#define LDBH(bb, nq) do { \
    bF[(nq)*2 + 0][0] = *(const bf16x8*)&(bb)[fro + ((nq)*2 + 0) * 1024];      \
    bF[(nq)*2 + 0][1] = *(const bf16x8*)&(bb)[fro + ((nq)*2 + 0) * 1024 + 32]; \
    bF[(nq)*2 + 1][0] = *(const bf16x8*)&(bb)[fro + ((nq)*2 + 1) * 1024];      \
    bF[(nq)*2 + 1][1] = *(const bf16x8*)&(bb)[fro + ((nq)*2 + 1) * 1024 + 32]; \
  } while (0)
#define MFMAQ(mq, nq) \
  _Pragma("unroll") \
  for (int mi_ = 0; mi_ < 4; mi_++) \
    _Pragma("unroll") \
    for (int ni_ = 0; ni_ < 2; ni_++) \
      _Pragma("unroll") \
      for (int kk_ = 0; kk_ < 2; kk_++) \
        acc[(mq)*4 + mi_][(nq)*2 + ni_] = __builtin_amdgcn_mfma_f32_16x16x32_bf16( \
            aF[mi_][kk_], bF[(nq)*2 + ni_][kk_], acc[(mq)*4 + mi_][(nq)*2 + ni_], 0, 0, 0);
#define BODY(mq, nq) do { \
    asm volatile("s_barrier" ::: "memory"); \
    asm volatile("s_waitcnt lgkmcnt(0)" ::: "memory"); \
    __builtin_amdgcn_sched_barrier(0); \
    __builtin_amdgcn_s_setprio(1); \
    MFMAQ(mq, nq); \
    __builtin_amdgcn_s_setprio(0); \
    asm volatile("s_barrier" ::: "memory"); \
  } while (0)

  // ---- prologue: stage Kt0, Kt1 entirely ----
  STAGE(0, 0); STAGE(0, 1); STAGE(0, 2); STAGE(0, 3);
  STAGE(1, 0); STAGE(1, 1); STAGE(1, 2); STAGE(1, 3);
  asm volatile("s_waitcnt vmcnt(8)" ::: "memory");
  asm volatile("s_barrier" ::: "memory");

  for (int i = 0; i < iters; ++i) {
    const int k1 = 2 * i + 1, k2 = 2 * i + 2, k3 = 2 * i + 3;
    const bool last = (i + 1 == iters);
    // P1 (0,0) buf0
    LDAH(aB0, 0); LDBH(bB0, 0); STG(k1, 1);
    BODY(0, 0);
    // P2 (0,1)
    LDBH(bB0, 1); STG(k1, 3);
    BODY(0, 1);
    // P3 (1,1)
    LDAH(aB0, 1); STG(k2, 2);
    BODY(1, 1);
    // P4 (1,0)  -- counted wait covers Kt(2i+1) before P5
    STG(k2, 0);
    if (last) { asm volatile("s_waitcnt vmcnt(0)" ::: "memory"); }
    else      { asm volatile("s_waitcnt vmcnt(4)" ::: "memory"); }
    BODY(1, 0);
    // P5 (0,0) buf1
    LDAH(aB1, 0); LDBH(bB1, 0); STG(k2, 1);
    BODY(0, 0);
    // P6 (0,1)
    LDBH(bB1, 1); STG(k2, 3);
    BODY(0, 1);
    // P7 (1,1)
    LDAH(aB1, 1); STG(k3, 2);
    BODY(1, 1);
    // P8 (1,0)  -- counted wait covers Kt(2i+2) before next P1
    STG(k3, 0);
    if (last) { asm volatile("s_waitcnt vmcnt(0)" ::: "memory"); }
    else      { asm volatile("s_waitcnt vmcnt(4)" ::: "memory"); }
    BODY(1, 0);
  }

#pragma unroll
  for (int m = 0; m < 8; m++)
#pragma unroll
    for (int n = 0; n < 4; n++)
      epi(bm + wmh * 128 + m * 16 + quad * 4, bn + wn * 64 + n * 16 + l16, kz, acc[m][n]);
#undef STAGE
#undef STG
#undef LDAH
#undef LDBH
#undef MFMAQ
#undef BODY
}

// ---------------- epilogues (rows m0..m0+3, col n) ----------------
struct EpiQKV {   // q[b,h,s,e] scaled by 0.125*log2(e); k[b,h,s,e]; v^T[b,h,e,s]
  u16 *q, *k, *vt; const float *bq, *bk, *bv;
  __device__ void operator()(int m0, int n, int, f32x4 v) const {
    const int which = n >> 10, nn = n & 1023;
    const int hh = nn >> 6, e = nn & 63;
    const int bb = m0 >> 11, s0 = m0 & 2047;
    const size_t bh = (size_t)(bb * 16 + hh);
    if (which == 0) {
      const float bias = bq[nn];
      u16* p = &q[(bh * 2048 + s0) * 64 + e];
#pragma unroll
      for (int r = 0; r < 4; r++) p[r * 64] = bf_bits((v[r] + bias) * 0.18033688f);
    } else if (which == 1) {
      const float bias = bk[nn];
      u16* p = &k[(bh * 2048 + s0) * 64 + e];
#pragma unroll
      for (int r = 0; r < 4; r++) p[r * 64] = bf_bits(v[r] + bias);
    } else {
      const float bias = bv[nn];
      bf16x4 pk;
#pragma unroll
      for (int r = 0; r < 4; r++) pk[r] = (__bf16)(v[r] + bias);
      *(bf16x4*)&vt[(bh * 64 + e) * 2048 + s0] = pk;
    }
  }
};
struct EpiPartB {  // bf16 split-K partial -> p + kz*4194304  ([4096,1024] bf16)
  u16* p;
  __device__ void operator()(int m0, int n, int kz, f32x4 v) const {
    u16* pp = p + (size_t)kz * 4194304;
#pragma unroll
    for (int r = 0; r < 4; r++) pp[(size_t)(m0 + r) * 1024 + n] = bf_bits(v[r]);
  }
};
struct EpiGelu {  // gelu(u) = u * sigmoid(2*c*(u+0.044715u^3)) via exp2
  const float* b1; u16* o;
  __device__ void operator()(int m0, int n, int, f32x4 v) const {
    const float bias = b1[n];
#pragma unroll
    for (int r = 0; r < 4; r++) {
      const float u = v[r] + bias;
      const float z2 = u * (2.3021183f + 0.10294515f * u * u);
      const float d = 1.0f + exp2_fast(-z2);
      o[(size_t)(m0 + r) * 4096 + n] = bf_bits(u * rcp_fast(d));
    }
  }
};

// ---------------- flash attention, no-max softmax, 1 wave = 32 q-rows ----------------
__global__ __launch_bounds__(256)
void attn_kernel(const u16* __restrict__ Q, const u16* __restrict__ K,
                 const u16* __restrict__ Vt, u16* __restrict__ O) {
  __shared__ __align__(16) u16 Ks[64 * 72];
  __shared__ __align__(16) u16 Vs[64 * 72];
  __shared__ __align__(16) u16 Ps[4][32 * 72];
  const int tid = threadIdx.x, wave = tid >> 6, lane = tid & 63;
  const int quad = lane >> 4, l16 = lane & 15;
  const int b = blockIdx.z, h = blockIdx.y, qt = blockIdx.x;
  const size_t bh = (size_t)(b * 16 + h);
  const u16* Qp = Q + bh * (size_t)(2048 * 64);
  const u16* Kp = K + bh * (size_t)(2048 * 64);
  const u16* Vp = Vt + bh * (size_t)(64 * 2048);
  const int q0 = qt * 128 + wave * 32;

  bf16x8 qf[2][2];
#pragma unroll
  for (int rg = 0; rg < 2; rg++) {
    const u16* qrow = &Qp[(size_t)(q0 + rg * 16 + l16) * 64 + quad * 8];
    qf[rg][0] = *(const bf16x8*)qrow;
    qf[rg][1] = *(const bf16x8*)(qrow + 32);
  }

  const int sr = tid >> 2, sc = (tid & 3) * 16;
  const int krow = 4 * (sr & 15) + (sr >> 4);          // permuted key row
  const u16* kg = &Kp[(size_t)krow * 64 + sc];
  const u16* vg = &Vp[(size_t)sr * 2048 + sc];
  u16* kl = &Ks[sr * 72 + sc];
  u16* vl = &Vs[sr * 72 + sc];
  u16* Pw = &Ps[wave][0];

  bf16x8 ones;
#pragma unroll
  for (int i = 0; i < 8; i++) ones[i] = (__bf16)1.0f;

  const f32x4 fz = {0.f, 0.f, 0.f, 0.f};
  f32x4 acc[2][4], lsum[2];
#pragma unroll
  for (int rg = 0; rg < 2; rg++) {
    lsum[rg] = fz;
#pragma unroll
    for (int g = 0; g < 4; g++) acc[rg][g] = fz;
  }

  bf16x8 pk0 = *(const bf16x8*)kg, pk1 = *(const bf16x8*)(kg + 8);
  bf16x8 pv0 = *(const bf16x8*)vg, pv1 = *(const bf16x8*)(vg + 8);

  for (int t0 = 0; t0 < 2048; t0 += 64) {
    *(bf16x8*)kl = pk0; *(bf16x8*)(kl + 8) = pk1;
    *(bf16x8*)vl = pv0; *(bf16x8*)(vl + 8) = pv1;
    __syncthreads();
    kg += 64 * 64; vg += 64;
    pk0 = *(const bf16x8*)kg; pk1 = *(const bf16x8*)(kg + 8);
    pv0 = *(const bf16x8*)vg; pv1 = *(const bf16x8*)(vg + 8);

    f32x4 s[2][4];
    __builtin_amdgcn_s_setprio(1);
#pragma unroll
    for (int g = 0; g < 4; g++) {
      const u16* kr = &Ks[(g * 16 + l16) * 72 + quad * 8];
      const bf16x8 kb0 = *(const bf16x8*)kr;
      const bf16x8 kb1 = *(const bf16x8*)(kr + 32);
#pragma unroll
      for (int rg = 0; rg < 2; rg++) {
        f32x4 z = __builtin_amdgcn_mfma_f32_16x16x32_bf16(qf[rg][0], kb0, fz, 0, 0, 0);
        s[rg][g] = __builtin_amdgcn_mfma_f32_16x16x32_bf16(qf[rg][1], kb1, z, 0, 0, 0);
      }
    }
    __builtin_amdgcn_s_setprio(0);
#pragma unroll
    for (int rg = 0; rg < 2; rg++)
#pragma unroll
      for (int r = 0; r < 4; r++) {
        f32x4 pf;
#pragma unroll
        for (int g = 0; g < 4; g++) pf[g] = exp2_fast(s[rg][g][r]);
        const bf16x4 pb = __builtin_convertvector(pf, bf16x4);
        *(bf16x4*)&Pw[(rg * 16 + quad * 4 + r) * 72 + 4 * l16] = pb;
      }
    bf16x8 pa[2][2];
#pragma unroll
    for (int rg = 0; rg < 2; rg++) {
      const u16* pr = &Pw[(rg * 16 + l16) * 72 + quad * 8];
      pa[rg][0] = *(const bf16x8*)pr;
      pa[rg][1] = *(const bf16x8*)(pr + 32);
      lsum[rg] = __builtin_amdgcn_mfma_f32_16x16x32_bf16(pa[rg][0], ones, lsum[rg], 0, 0, 0);
      lsum[rg] = __builtin_amdgcn_mfma_f32_16x16x32_bf16(pa[rg][1], ones, lsum[rg], 0, 0, 0);
    }
    __builtin_amdgcn_s_setprio(1);
#pragma unroll
    for (int g = 0; g < 4; g++) {
      const u16* vr = &Vs[(g * 16 + l16) * 72 + quad * 8];
      const bf16x8 vb0 = *(const bf16x8*)vr;
      const bf16x8 vb1 = *(const bf16x8*)(vr + 32);
#pragma unroll
      for (int rg = 0; rg < 2; rg++) {
        acc[rg][g] = __builtin_amdgcn_mfma_f32_16x16x32_bf16(pa[rg][0], vb0, acc[rg][g], 0, 0, 0);
        acc[rg][g] = __builtin_amdgcn_mfma_f32_16x16x32_bf16(pa[rg][1], vb1, acc[rg][g], 0, 0, 0);
      }
    }
    __builtin_amdgcn_s_setprio(0);
    __syncthreads();
  }
#pragma unroll
  for (int rg = 0; rg < 2; rg++)
#pragma unroll
    for (int r = 0; r < 4; r++) {
      const float inv = rcp_fast(lsum[rg][r]);
      const int s_row = q0 + rg * 16 + quad * 4 + r;
      u16* op = (u16*)&O[((size_t)(b * 2048 + s_row)) * 1024 + h * 64 + l16];
#pragma unroll
      for (int g = 0; g < 4; g++) op[g * 16] = bf_bits(acc[rg][g][r] * inv);
    }
}

// ---------------- launch ----------------
extern "C" void kernel_launch(void* const* d_in, const int* in_sizes, int n_in,
                              void* d_out, int out_size, void* d_ws, size_t ws_size,
                              hipStream_t stream) {
  const float* x   = (const float*)d_in[0];
  const float* Wq  = (const float*)d_in[1];
  const float* bq  = (const float*)d_in[2];
  const float* Wk  = (const float*)d_in[3];
  const float* bk  = (const float*)d_in[4];
  const float* Wv  = (const float*)d_in[5];
  const float* bv  = (const float*)d_in[6];
  const float* Wo  = (const float*)d_in[7];
  const float* bo  = (const float*)d_in[8];
  const float* g1  = (const float*)d_in[9];
  const float* be1 = (const float*)d_in[10];
  const float* W1  = (const float*)d_in[11];
  const float* b1  = (const float*)d_in[12];
  const float* W2  = (const float*)d_in[13];
  const float* b2  = (const float*)d_in[14];
  const float* g2  = (const float*)d_in[15];
  const float* be2 = (const float*)d_in[16];
  float* out = (float*)d_out;

  char* w = (char*)d_ws;
  u16* wqkv = (u16*)w; w += (size_t)3072 * 1024 * 2;   // contiguous bf16 weights:
  u16* wob  = (u16*)w; w += (size_t)1024 * 1024 * 2;   //   wqkv|wob|w1b|w2b
  u16* w1b  = (u16*)w; w += (size_t)4096 * 1024 * 2;
  u16* w2b  = (u16*)w; w += (size_t)1024 * 4096 * 2;
  u16* hb   = (u16*)w; w += (size_t)4096 * 1024 * 2;
  u16* qb   = (u16*)w; w += (size_t)4096 * 1024 * 2;   // later: MLP2 partials (4x8MB
  u16* kb   = (u16*)w; w += (size_t)4096 * 1024 * 2;   //   bf16 spanning qb..atb)
  u16* vtb  = (u16*)w; w += (size_t)4096 * 1024 * 2;
  u16* atb  = (u16*)w; w += (size_t)4096 * 1024 * 2;
  u16* m1b  = (u16*)w; w += (size_t)4096 * 4096 * 2;   // O-proj partials first (4x8MB)

  u16* op_part = m1b;   // O-proj bf16 partials, dead before MLP1 writes m1b
  u16* ml_part = qb;    // MLP2 bf16 partials, qb..atb all dead after O-proj

  f2b_all<<<12288, 256, 0, stream>>>(Wq, Wk, Wv, Wo, W1, W2, wqkv);

  ln_kernel<<<4096, 256, 0, stream>>>(x, g1, be1, hb);
  // QKV: M=4096, N=3072, K=1024 -> grid 16*12 = 192
  gemm8<EpiQKV><<<192, 512, 0, stream>>>(hb, wqkv, 1024, 1024, 12,
      EpiQKV{qb, kb, vtb, bq, bk, bv});
  attn_kernel<<<dim3(16, 16, 2), 256, 0, stream>>>(qb, kb, vtb, atb);
  // O-proj: N=1024, K=1024 split 4 -> grid 16*4*4 = 256
  gemm8<EpiPartB><<<256, 512, 0, stream>>>(atb, wob, 1024, 256, 4,
      EpiPartB{op_part});
  ln_fuse<<<4096, 256, 0, stream>>>(x, op_part, bo, g2, be2, out, hb);
  // MLP1: N=4096, K=1024 -> grid 16*16 = 256
  gemm8<EpiGelu><<<256, 512, 0, stream>>>(hb, w1b, 1024, 1024, 16,
      EpiGelu{b1, m1b});
  // MLP2: N=1024, K=4096 split 4 -> grid 16*4*4 = 256
  gemm8<EpiPartB><<<256, 512, 0, stream>>>(m1b, w2b, 4096, 1024, 4,
      EpiPartB{ml_part});
  add4<<<4096, 256, 0, stream>>>(out, ml_part, b2);
}

// Round 5
// 340.988 us; speedup vs baseline: 1.3323x; 1.3323x over previous
//
#include <hip/hip_runtime.h>

typedef unsigned short u16;
typedef __attribute__((ext_vector_type(8))) __bf16 bf16x8;
typedef __attribute__((ext_vector_type(4))) __bf16 bf16x4;
typedef __attribute__((ext_vector_type(4))) float f32x4;
typedef __attribute__((ext_vector_type(4))) unsigned short u16x4;

#define AS1 __attribute__((address_space(1)))
#define AS3 __attribute__((address_space(3)))

__device__ __forceinline__ void async_load16(const void* g, void* l) {
  __builtin_amdgcn_global_load_lds((const AS1 void*)g, (AS3 void*)l, 16, 0, 0);
}

__device__ __forceinline__ float exp2_fast(float x) {
#if __has_builtin(__builtin_amdgcn_exp2f)
  return __builtin_amdgcn_exp2f(x);
#else
  return exp2f(x);
#endif
}
__device__ __forceinline__ float rcp_fast(float x) {
#if __has_builtin(__builtin_amdgcn_rcpf)
  return __builtin_amdgcn_rcpf(x);
#else
  return 1.0f / x;
#endif
}

__device__ __forceinline__ u16 f2bf(float f) {   // manual RNE
  union { float f; unsigned u; } a; a.f = f;
  unsigned u = a.u;
  u += 0x7fffu + ((u >> 16) & 1u);
  return (u16)(u >> 16);
}
__device__ __forceinline__ u16 bf_bits(float f) {  // native cvt (RNE)
  union { __bf16 b; u16 u; } c; c.b = (__bf16)f; return c.u;
}
__device__ __forceinline__ float bf2f(u16 h) {
  union { unsigned u; float f; } c; c.u = ((unsigned)h) << 16; return c.f;
}

// ------- fp32 -> bf16: all 6 weights in ONE launch (dst contiguous in ws) -------
__global__ __launch_bounds__(256)
void f2b_all(const float* __restrict__ s0, const float* __restrict__ s1,
             const float* __restrict__ s2, const float* __restrict__ s3,
             const float* __restrict__ s4, const float* __restrict__ s5,
             u16* __restrict__ dst) {
  const int i = blockIdx.x * 256 + threadIdx.x;   // < 3145728
  const float* s; int off;
  if (i < 1048576) {
    if (i < 262144)      { s = s0; off = i; }
    else if (i < 524288) { s = s1; off = i - 262144; }
    else if (i < 786432) { s = s2; off = i - 524288; }
    else                 { s = s3; off = i - 786432; }
  } else if (i < 2097152) { s = s4; off = i - 1048576; }
  else                    { s = s5; off = i - 2097152; }
  const float4 v = ((const float4*)s)[off];
  u16x4 o; o[0] = f2bf(v.x); o[1] = f2bf(v.y); o[2] = f2bf(v.z); o[3] = f2bf(v.w);
  ((u16x4*)dst)[i] = o;
}

// ---------------- LayerNorm (1024 cols, 1 block/row) ----------------
__global__ __launch_bounds__(256)
void ln_kernel(const float* __restrict__ x, const float* __restrict__ g,
               const float* __restrict__ b, u16* __restrict__ out) {
  const int row = blockIdx.x, tid = threadIdx.x;
  const float4 v = ((const float4*)(x + (size_t)row * 1024))[tid];
  float s = v.x + v.y + v.z + v.w;
  float s2 = v.x * v.x + v.y * v.y + v.z * v.z + v.w * v.w;
#pragma unroll
  for (int o = 1; o < 64; o <<= 1) { s += __shfl_xor(s, o); s2 += __shfl_xor(s2, o); }
  __shared__ float red[8];
  const int wave = tid >> 6, lane = tid & 63;
  if (lane == 0) { red[wave] = s; red[wave + 4] = s2; }
  __syncthreads();
  s = red[0] + red[1] + red[2] + red[3];
  s2 = red[4] + red[5] + red[6] + red[7];
  const float mu = s * (1.f / 1024.f);
  const float rstd = rsqrtf(s2 * (1.f / 1024.f) - mu * mu + 1e-5f);
  const float4 gg = ((const float4*)g)[tid];
  const float4 bb = ((const float4*)b)[tid];
  u16x4 o4;
  o4[0] = f2bf((v.x - mu) * rstd * gg.x + bb.x);
  o4[1] = f2bf((v.y - mu) * rstd * gg.y + bb.y);
  o4[2] = f2bf((v.z - mu) * rstd * gg.z + bb.z);
  o4[3] = f2bf((v.w - mu) * rstd * gg.w + bb.w);
  ((u16x4*)(out + (size_t)row * 1024))[tid] = o4;
}

// -- fused: out = x + p[0] + p[1] + bo (bf16 partials); hb = LN(out; g,b) --
__global__ __launch_bounds__(256)
void ln_fuse(const float* __restrict__ x, const u16* __restrict__ parts,
             const float* __restrict__ bo, const float* __restrict__ g,
             const float* __restrict__ b, float* __restrict__ out,
             u16* __restrict__ hb) {
  const int row = blockIdx.x, tid = threadIdx.x;
  const size_t base = (size_t)row * 1024;
  const int i4 = row * 256 + tid;
  const float4 xv = ((const float4*)(x + base))[tid];
  const u16x4 h0 = ((const u16x4*)parts)[i4];
  const u16x4 h1 = ((const u16x4*)(parts + 4194304))[i4];
  const float4 bv = ((const float4*)bo)[tid];
  float4 t;
  t.x = xv.x + bf2f(h0[0]) + bf2f(h1[0]) + bv.x;
  t.y = xv.y + bf2f(h0[1]) + bf2f(h1[1]) + bv.y;
  t.z = xv.z + bf2f(h0[2]) + bf2f(h1[2]) + bv.z;
  t.w = xv.w + bf2f(h0[3]) + bf2f(h1[3]) + bv.w;
  ((float4*)(out + base))[tid] = t;
  float s = t.x + t.y + t.z + t.w;
  float s2 = t.x * t.x + t.y * t.y + t.z * t.z + t.w * t.w;
#pragma unroll
  for (int o = 1; o < 64; o <<= 1) { s += __shfl_xor(s, o); s2 += __shfl_xor(s2, o); }
  __shared__ float red[8];
  const int wave = tid >> 6, lane = tid & 63;
  if (lane == 0) { red[wave] = s; red[wave + 4] = s2; }
  __syncthreads();
  s = red[0] + red[1] + red[2] + red[3];
  s2 = red[4] + red[5] + red[6] + red[7];
  const float mu = s * (1.f / 1024.f);
  const float rstd = rsqrtf(s2 * (1.f / 1024.f) - mu * mu + 1e-5f);
  const float4 gg = ((const float4*)g)[tid];
  const float4 bb = ((const float4*)b)[tid];
  u16x4 o4;
  o4[0] = f2bf((t.x - mu) * rstd * gg.x + bb.x);
  o4[1] = f2bf((t.y - mu) * rstd * gg.y + bb.y);
  o4[2] = f2bf((t.z - mu) * rstd * gg.z + bb.z);
  o4[3] = f2bf((t.w - mu) * rstd * gg.w + bb.w);
  ((u16x4*)(hb + base))[tid] = o4;
}

// ------- out += p[0..3] + b2 (MLP2 reduction over 4 bf16 partial slices) -------
__global__ __launch_bounds__(256)
void add4(float* __restrict__ out, const u16* __restrict__ p,
          const float* __restrict__ b2) {
  const int i = blockIdx.x * 256 + threadIdx.x;   // f4 index < 1048576
  const float4 o = ((const float4*)out)[i];
  const float4 bv = ((const float4*)b2)[i & 255];
  float a0 = o.x + bv.x, a1 = o.y + bv.y, a2 = o.z + bv.z, a3 = o.w + bv.w;
#pragma unroll
  for (int kz = 0; kz < 4; kz++) {
    const u16x4 h = ((const u16x4*)(p + (size_t)kz * 4194304))[i];
    a0 += bf2f(h[0]); a1 += bf2f(h[1]); a2 += bf2f(h[2]); a3 += bf2f(h[3]);
  }
  float4 r; r.x = a0; r.y = a1; r.z = a2; r.w = a3;
  ((float4*)out)[i] = r;
}

// ---------------- GEMM C = A * B^T, A[M,ldk] bf16, B[N,ldk] bf16 ----------------
// BM=256, BN=128, BK=64; 4 waves, wave tile 64x128 (acc 4x8). Proven 2-barrier
// m97-style structure; BK=64 halves the per-K-step barrier-drain count vs BK=32.
// LDS rows are 64 u16 (128B) -> both-sides XOR swizzle: staging thread (srow,
// chunk) loads global 16B-chunk (chunk^srow) into linear LDS slot chunk (dest
// stays wave-uniform for global_load_lds, m104/m108); fragment reads address
// slot ((kk*4+quad)^(l16&7)). LDS[row][slot] holds global chunk slot^(row&7).
// M fixed = 4096 (16 m-blocks); grid id = m + 16*(n + NB*kz).
template <class Epi>
__global__ __launch_bounds__(256, 2)
void gemm_bt(const u16* __restrict__ A, const u16* __restrict__ Bw,
             int ldk, int K, int NB, Epi epi) {
  __shared__ __align__(16) u16 As[256 * 64];   // 32 KB
  __shared__ __align__(16) u16 Bs[128 * 64];   // 16 KB
  const int tid = threadIdx.x;
  const int wave = tid >> 6, lane = tid & 63;
  const int quad = lane >> 4, l16 = lane & 15;
  const int id = blockIdx.x;
  const int mb = id & 15;
  const int t = id >> 4;
  const int nb = t % NB;
  const int kz = t / NB;
  const int bm = mb * 256, bn = nb * 128;
  const int wm = wave * 64;

  const int srow = lane >> 3;                 // 0..7
  const int chunk = lane & 7;                 // 16B chunk slot this lane fills
  const int scol = ((chunk ^ srow) * 8);      // inverse-swizzled global col
  // A: 8 staging instrs/thread (rows wave*64 + j*8 + srow)
  const u16* pa[8];
  u16* la[8];
#pragma unroll
  for (int j = 0; j < 8; j++) {
    pa[j] = A + (size_t)(bm + wave * 64 + j * 8 + srow) * ldk + (size_t)kz * K + scol;
    la[j] = &As[wave * 4096 + j * 512];       // wave-uniform dest
  }
  // B: 4 staging instrs/thread (rows wave*32 + j*8 + srow)
  const u16* pb[4];
  u16* lb[4];
#pragma unroll
  for (int j = 0; j < 4; j++) {
    pb[j] = Bw + (size_t)(bn + wave * 32 + j * 8 + srow) * ldk + (size_t)kz * K + scol;
    lb[j] = &Bs[wave * 2048 + j * 512];
  }

  const f32x4 fz = {0.f, 0.f, 0.f, 0.f};
  f32x4 acc[4][8];
#pragma unroll
  for (int i = 0; i < 4; i++)
#pragma unroll
    for (int j = 0; j < 8; j++) acc[i][j] = fz;

  const int key = (l16 & 7);                  // row&7 for fragment rows

  for (int k0 = 0; k0 < K; k0 += 64) {
#pragma unroll
    for (int j = 0; j < 8; j++) { async_load16(pa[j], la[j]); pa[j] += 64; }
#pragma unroll
    for (int j = 0; j < 4; j++) { async_load16(pb[j], lb[j]); pb[j] += 64; }
    __syncthreads();
#pragma unroll
    for (int kk = 0; kk < 2; kk++) {
      const int slot = ((kk * 4 + quad) ^ key) * 8;
      bf16x8 af[4], bfr[8];
#pragma unroll
      for (int mi = 0; mi < 4; mi++)
        af[mi] = *(const bf16x8*)&As[(wm + mi * 16 + l16) * 64 + slot];
#pragma unroll
      for (int ni = 0; ni < 8; ni++)
        bfr[ni] = *(const bf16x8*)&Bs[(ni * 16 + l16) * 64 + slot];
#pragma unroll
      for (int mi = 0; mi < 4; mi++)
#pragma unroll
        for (int ni = 0; ni < 8; ni++)
          acc[mi][ni] = __builtin_amdgcn_mfma_f32_16x16x32_bf16(af[mi], bfr[ni], acc[mi][ni], 0, 0, 0);
    }
    __syncthreads();
  }
#pragma unroll
  for (int mi = 0; mi < 4; mi++)
#pragma unroll
    for (int ni = 0; ni < 8; ni++)
      epi(bm + wm + mi * 16 + quad * 4, bn + ni * 16 + l16, kz, acc[mi][ni]);
}

// ---------------- epilogues (rows m0..m0+3, col n) ----------------
struct EpiQKV {   // q[b,h,s,e] scaled by 0.125*log2(e); k[b,h,s,e]; v^T[b,h,e,s]
  u16 *q, *k, *vt; const float *bq, *bk, *bv;
  __device__ void operator()(int m0, int n, int, f32x4 v) const {
    const int which = n >> 10, nn = n & 1023;
    const int hh = nn >> 6, e = nn & 63;
    const int bb = m0 >> 11, s0 = m0 & 2047;
    const size_t bh = (size_t)(bb * 16 + hh);
    if (which == 0) {
      const float bias = bq[nn];
      u16* p = &q[(bh * 2048 + s0) * 64 + e];
#pragma unroll
      for (int r = 0; r < 4; r++) p[r * 64] = bf_bits((v[r] + bias) * 0.18033688f);
    } else if (which == 1) {
      const float bias = bk[nn];
      u16* p = &k[(bh * 2048 + s0) * 64 + e];
#pragma unroll
      for (int r = 0; r < 4; r++) p[r * 64] = bf_bits(v[r] + bias);
    } else {
      const float bias = bv[nn];
      bf16x4 pk;
#pragma unroll
      for (int r = 0; r < 4; r++) pk[r] = (__bf16)(v[r] + bias);
      *(bf16x4*)&vt[(bh * 64 + e) * 2048 + s0] = pk;
    }
  }
};
struct EpiPartB {  // bf16 split-K partial -> p + kz*4194304  ([4096,1024] bf16)
  u16* p;
  __device__ void operator()(int m0, int n, int kz, f32x4 v) const {
    u16* pp = p + (size_t)kz * 4194304;
#pragma unroll
    for (int r = 0; r < 4; r++) pp[(size_t)(m0 + r) * 1024 + n] = bf_bits(v[r]);
  }
};
struct EpiGelu {  // gelu(u) = u * sigmoid(2*c*(u+0.044715u^3)) via exp2
  const float* b1; u16* o;
  __device__ void operator()(int m0, int n, int, f32x4 v) const {
    const float bias = b1[n];
#pragma unroll
    for (int r = 0; r < 4; r++) {
      const float u = v[r] + bias;
      const float z2 = u * (2.3021183f + 0.10294515f * u * u);
      const float d = 1.0f + exp2_fast(-z2);
      o[(size_t)(m0 + r) * 4096 + n] = bf_bits(u * rcp_fast(d));
    }
  }
};

// ---------------- flash attention, no-max softmax, 1 wave = 32 q-rows ----------------
__global__ __launch_bounds__(256)
void attn_kernel(const u16* __restrict__ Q, const u16* __restrict__ K,
                 const u16* __restrict__ Vt, u16* __restrict__ O) {
  __shared__ __align__(16) u16 Ks[64 * 72];
  __shared__ __align__(16) u16 Vs[64 * 72];
  __shared__ __align__(16) u16 Ps[4][32 * 72];
  const int tid = threadIdx.x, wave = tid >> 6, lane = tid & 63;
  const int quad = lane >> 4, l16 = lane & 15;
  const int b = blockIdx.z, h = blockIdx.y, qt = blockIdx.x;
  const size_t bh = (size_t)(b * 16 + h);
  const u16* Qp = Q + bh * (size_t)(2048 * 64);
  const u16* Kp = K + bh * (size_t)(2048 * 64);
  const u16* Vp = Vt + bh * (size_t)(64 * 2048);
  const int q0 = qt * 128 + wave * 32;

  bf16x8 qf[2][2];
#pragma unroll
  for (int rg = 0; rg < 2; rg++) {
    const u16* qrow = &Qp[(size_t)(q0 + rg * 16 + l16) * 64 + quad * 8];
    qf[rg][0] = *(const bf16x8*)qrow;
    qf[rg][1] = *(const bf16x8*)(qrow + 32);
  }

  const int sr = tid >> 2, sc = (tid & 3) * 16;
  const int krow = 4 * (sr & 15) + (sr >> 4);          // permuted key row
  const u16* kg = &Kp[(size_t)krow * 64 + sc];
  const u16* vg = &Vp[(size_t)sr * 2048 + sc];
  u16* kl = &Ks[sr * 72 + sc];
  u16* vl = &Vs[sr * 72 + sc];
  u16* Pw = &Ps[wave][0];

  bf16x8 ones;
#pragma unroll
  for (int i = 0; i < 8; i++) ones[i] = (__bf16)1.0f;

  const f32x4 fz = {0.f, 0.f, 0.f, 0.f};
  f32x4 acc[2][4], lsum[2];
#pragma unroll
  for (int rg = 0; rg < 2; rg++) {
    lsum[rg] = fz;
#pragma unroll
    for (int g = 0; g < 4; g++) acc[rg][g] = fz;
  }

  bf16x8 pk0 = *(const bf16x8*)kg, pk1 = *(const bf16x8*)(kg + 8);
  bf16x8 pv0 = *(const bf16x8*)vg, pv1 = *(const bf16x8*)(vg + 8);

  for (int t0 = 0; t0 < 2048; t0 += 64) {
    *(bf16x8*)kl = pk0; *(bf16x8*)(kl + 8) = pk1;
    *(bf16x8*)vl = pv0; *(bf16x8*)(vl + 8) = pv1;
    __syncthreads();
    kg += 64 * 64; vg += 64;
    pk0 = *(const bf16x8*)kg; pk1 = *(const bf16x8*)(kg + 8);
    pv0 = *(const bf16x8*)vg; pv1 = *(const bf16x8*)(vg + 8);

    f32x4 s[2][4];
    __builtin_amdgcn_s_setprio(1);
#pragma unroll
    for (int g = 0; g < 4; g++) {
      const u16* kr = &Ks[(g * 16 + l16) * 72 + quad * 8];
      const bf16x8 kb0 = *(const bf16x8*)kr;
      const bf16x8 kb1 = *(const bf16x8*)(kr + 32);
#pragma unroll
      for (int rg = 0; rg < 2; rg++) {
        f32x4 z = __builtin_amdgcn_mfma_f32_16x16x32_bf16(qf[rg][0], kb0, fz, 0, 0, 0);
        s[rg][g] = __builtin_amdgcn_mfma_f32_16x16x32_bf16(qf[rg][1], kb1, z, 0, 0, 0);
      }
    }
    __builtin_amdgcn_s_setprio(0);
#pragma unroll
    for (int rg = 0; rg < 2; rg++)
#pragma unroll
      for (int r = 0; r < 4; r++) {
        f32x4 pf;
#pragma unroll
        for (int g = 0; g < 4; g++) pf[g] = exp2_fast(s[rg][g][r]);
        const bf16x4 pb = __builtin_convertvector(pf, bf16x4);
        *(bf16x4*)&Pw[(rg * 16 + quad * 4 + r) * 72 + 4 * l16] = pb;
      }
    bf16x8 pa[2][2];
#pragma unroll
    for (int rg = 0; rg < 2; rg++) {
      const u16* pr = &Pw[(rg * 16 + l16) * 72 + quad * 8];
      pa[rg][0] = *(const bf16x8*)pr;
      pa[rg][1] = *(const bf16x8*)(pr + 32);
      lsum[rg] = __builtin_amdgcn_mfma_f32_16x16x32_bf16(pa[rg][0], ones, lsum[rg], 0, 0, 0);
      lsum[rg] = __builtin_amdgcn_mfma_f32_16x16x32_bf16(pa[rg][1], ones, lsum[rg], 0, 0, 0);
    }
    __builtin_amdgcn_s_setprio(1);
#pragma unroll
    for (int g = 0; g < 4; g++) {
      const u16* vr = &Vs[(g * 16 + l16) * 72 + quad * 8];
      const bf16x8 vb0 = *(const bf16x8*)vr;
      const bf16x8 vb1 = *(const bf16x8*)(vr + 32);
#pragma unroll
      for (int rg = 0; rg < 2; rg++) {
        acc[rg][g] = __builtin_amdgcn_mfma_f32_16x16x32_bf16(pa[rg][0], vb0, acc[rg][g], 0, 0, 0);
        acc[rg][g] = __builtin_amdgcn_mfma_f32_16x16x32_bf16(pa[rg][1], vb1, acc[rg][g], 0, 0, 0);
      }
    }
    __builtin_amdgcn_s_setprio(0);
    __syncthreads();
  }
#pragma unroll
  for (int rg = 0; rg < 2; rg++)
#pragma unroll
    for (int r = 0; r < 4; r++) {
      const float inv = rcp_fast(lsum[rg][r]);
      const int s_row = q0 + rg * 16 + quad * 4 + r;
      u16* op = (u16*)&O[((size_t)(b * 2048 + s_row)) * 1024 + h * 64 + l16];
#pragma unroll
      for (int g = 0; g < 4; g++) op[g * 16] = bf_bits(acc[rg][g][r] * inv);
    }
}

// ---------------- launch ----------------
extern "C" void kernel_launch(void* const* d_in, const int* in_sizes, int n_in,
                              void* d_out, int out_size, void* d_ws, size_t ws_size,
                              hipStream_t stream) {
  const float* x   = (const float*)d_in[0];
  const float* Wq  = (const float*)d_in[1];
  const float* bq  = (const float*)d_in[2];
  const float* Wk  = (const float*)d_in[3];
  const float* bk  = (const float*)d_in[4];
  const float* Wv  = (const float*)d_in[5];
  const float* bv  = (const float*)d_in[6];
  const float* Wo  = (const float*)d_in[7];
  const float* bo  = (const float*)d_in[8];
  const float* g1  = (const float*)d_in[9];
  const float* be1 = (const float*)d_in[10];
  const float* W1  = (const float*)d_in[11];
  const float* b1  = (const float*)d_in[12];
  const float* W2  = (const float*)d_in[13];
  const float* b2  = (const float*)d_in[14];
  const float* g2  = (const float*)d_in[15];
  const float* be2 = (const float*)d_in[16];
  float* out = (float*)d_out;

  char* w = (char*)d_ws;
  u16* wqkv = (u16*)w; w += (size_t)3072 * 1024 * 2;   // contiguous bf16 weights:
  u16* wob  = (u16*)w; w += (size_t)1024 * 1024 * 2;   //   wqkv|wob|w1b|w2b
  u16* w1b  = (u16*)w; w += (size_t)4096 * 1024 * 2;
  u16* w2b  = (u16*)w; w += (size_t)1024 * 4096 * 2;
  u16* hb   = (u16*)w; w += (size_t)4096 * 1024 * 2;
  u16* qb   = (u16*)w; w += (size_t)4096 * 1024 * 2;   // later: MLP2 partials (4x8MB
  u16* kb   = (u16*)w; w += (size_t)4096 * 1024 * 2;   //   bf16 spanning qb..atb)
  u16* vtb  = (u16*)w; w += (size_t)4096 * 1024 * 2;
  u16* atb  = (u16*)w; w += (size_t)4096 * 1024 * 2;
  u16* m1b  = (u16*)w; w += (size_t)4096 * 4096 * 2;   // O-proj partials first (2x8MB)

  u16* op_part = m1b;   // O-proj bf16 partials, dead before MLP1 writes m1b
  u16* ml_part = qb;    // MLP2 bf16 partials, qb..atb all dead after O-proj

  f2b_all<<<12288, 256, 0, stream>>>(Wq, Wk, Wv, Wo, W1, W2, wqkv);

  ln_kernel<<<4096, 256, 0, stream>>>(x, g1, be1, hb);
  // QKV: M=4096, N=3072, K=1024 -> grid 16*24 = 384
  gemm_bt<EpiQKV><<<384, 256, 0, stream>>>(hb, wqkv, 1024, 1024, 24,
      EpiQKV{qb, kb, vtb, bq, bk, bv});
  attn_kernel<<<dim3(16, 16, 2), 256, 0, stream>>>(qb, kb, vtb, atb);
  // O-proj: N=1024, K=1024 split 2 -> grid 16*8*2 = 256
  gemm_bt<EpiPartB><<<256, 256, 0, stream>>>(atb, wob, 1024, 512, 8,
      EpiPartB{op_part});
  ln_fuse<<<4096, 256, 0, stream>>>(x, op_part, bo, g2, be2, out, hb);
  // MLP1: N=4096, K=1024 -> grid 16*32 = 512
  gemm_bt<EpiGelu><<<512, 256, 0, stream>>>(hb, w1b, 1024, 1024, 32,
      EpiGelu{b1, m1b});
  // MLP2: N=1024, K=4096 split 4 -> grid 16*8*4 = 512
  gemm_bt<EpiPartB><<<512, 256, 0, stream>>>(m1b, w2b, 4096, 1024, 8,
      EpiPartB{ml_part});
  add4<<<4096, 256, 0, stream>>>(out, ml_part, b2);
}

// Round 6
// 333.894 us; speedup vs baseline: 1.3606x; 1.0212x over previous
//
#include <hip/hip_runtime.h>

typedef unsigned short u16;
typedef __attribute__((ext_vector_type(8))) __bf16 bf16x8;
typedef __attribute__((ext_vector_type(4))) __bf16 bf16x4;
typedef __attribute__((ext_vector_type(4))) float f32x4;
typedef __attribute__((ext_vector_type(4))) unsigned short u16x4;

#define AS1 __attribute__((address_space(1)))
#define AS3 __attribute__((address_space(3)))

__device__ __forceinline__ void async_load16(const void* g, void* l) {
  __builtin_amdgcn_global_load_lds((const AS1 void*)g, (AS3 void*)l, 16, 0, 0);
}

__device__ __forceinline__ float exp2_fast(float x) {
#if __has_builtin(__builtin_amdgcn_exp2f)
  return __builtin_amdgcn_exp2f(x);
#else
  return exp2f(x);
#endif
}
__device__ __forceinline__ float rcp_fast(float x) {
#if __has_builtin(__builtin_amdgcn_rcpf)
  return __builtin_amdgcn_rcpf(x);
#else
  return 1.0f / x;
#endif
}

__device__ __forceinline__ u16 f2bf(float f) {   // manual RNE
  union { float f; unsigned u; } a; a.f = f;
  unsigned u = a.u;
  u += 0x7fffu + ((u >> 16) & 1u);
  return (u16)(u >> 16);
}
__device__ __forceinline__ u16 bf_bits(float f) {  // native cvt (RNE)
  union { __bf16 b; u16 u; } c; c.b = (__bf16)f; return c.u;
}
__device__ __forceinline__ float bf2f(u16 h) {
  union { unsigned u; float f; } c; c.u = ((unsigned)h) << 16; return c.f;
}

// ------- fp32 -> bf16: all 6 weights in ONE launch (dst contiguous in ws) -------
__global__ __launch_bounds__(256)
void f2b_all(const float* __restrict__ s0, const float* __restrict__ s1,
             const float* __restrict__ s2, const float* __restrict__ s3,
             const float* __restrict__ s4, const float* __restrict__ s5,
             u16* __restrict__ dst) {
  const int i = blockIdx.x * 256 + threadIdx.x;   // < 3145728
  const float* s; int off;
  if (i < 1048576) {
    if (i < 262144)      { s = s0; off = i; }
    else if (i < 524288) { s = s1; off = i - 262144; }
    else if (i < 786432) { s = s2; off = i - 524288; }
    else                 { s = s3; off = i - 786432; }
  } else if (i < 2097152) { s = s4; off = i - 1048576; }
  else                    { s = s5; off = i - 2097152; }
  const float4 v = ((const float4*)s)[off];
  u16x4 o; o[0] = f2bf(v.x); o[1] = f2bf(v.y); o[2] = f2bf(v.z); o[3] = f2bf(v.w);
  ((u16x4*)dst)[i] = o;
}

// ---------------- LayerNorm (1024 cols, 1 block/row) ----------------
__global__ __launch_bounds__(256)
void ln_kernel(const float* __restrict__ x, const float* __restrict__ g,
               const float* __restrict__ b, u16* __restrict__ out) {
  const int row = blockIdx.x, tid = threadIdx.x;
  const float4 v = ((const float4*)(x + (size_t)row * 1024))[tid];
  float s = v.x + v.y + v.z + v.w;
  float s2 = v.x * v.x + v.y * v.y + v.z * v.z + v.w * v.w;
#pragma unroll
  for (int o = 1; o < 64; o <<= 1) { s += __shfl_xor(s, o); s2 += __shfl_xor(s2, o); }
  __shared__ float red[8];
  const int wave = tid >> 6, lane = tid & 63;
  if (lane == 0) { red[wave] = s; red[wave + 4] = s2; }
  __syncthreads();
  s = red[0] + red[1] + red[2] + red[3];
  s2 = red[4] + red[5] + red[6] + red[7];
  const float mu = s * (1.f / 1024.f);
  const float rstd = rsqrtf(s2 * (1.f / 1024.f) - mu * mu + 1e-5f);
  const float4 gg = ((const float4*)g)[tid];
  const float4 bb = ((const float4*)b)[tid];
  u16x4 o4;
  o4[0] = f2bf((v.x - mu) * rstd * gg.x + bb.x);
  o4[1] = f2bf((v.y - mu) * rstd * gg.y + bb.y);
  o4[2] = f2bf((v.z - mu) * rstd * gg.z + bb.z);
  o4[3] = f2bf((v.w - mu) * rstd * gg.w + bb.w);
  ((u16x4*)(out + (size_t)row * 1024))[tid] = o4;
}

// -- fused: out = x + p[0] + p[1] + bo (bf16 partials); hb = LN(out; g,b) --
__global__ __launch_bounds__(256)
void ln_fuse(const float* __restrict__ x, const u16* __restrict__ parts,
             const float* __restrict__ bo, const float* __restrict__ g,
             const float* __restrict__ b, float* __restrict__ out,
             u16* __restrict__ hb) {
  const int row = blockIdx.x, tid = threadIdx.x;
  const size_t base = (size_t)row * 1024;
  const int i4 = row * 256 + tid;
  const float4 xv = ((const float4*)(x + base))[tid];
  const u16x4 h0 = ((const u16x4*)parts)[i4];
  const u16x4 h1 = ((const u16x4*)(parts + 4194304))[i4];
  const float4 bv = ((const float4*)bo)[tid];
  float4 t;
  t.x = xv.x + bf2f(h0[0]) + bf2f(h1[0]) + bv.x;
  t.y = xv.y + bf2f(h0[1]) + bf2f(h1[1]) + bv.y;
  t.z = xv.z + bf2f(h0[2]) + bf2f(h1[2]) + bv.z;
  t.w = xv.w + bf2f(h0[3]) + bf2f(h1[3]) + bv.w;
  ((float4*)(out + base))[tid] = t;
  float s = t.x + t.y + t.z + t.w;
  float s2 = t.x * t.x + t.y * t.y + t.z * t.z + t.w * t.w;
#pragma unroll
  for (int o = 1; o < 64; o <<= 1) { s += __shfl_xor(s, o); s2 += __shfl_xor(s2, o); }
  __shared__ float red[8];
  const int wave = tid >> 6, lane = tid & 63;
  if (lane == 0) { red[wave] = s; red[wave + 4] = s2; }
  __syncthreads();
  s = red[0] + red[1] + red[2] + red[3];
  s2 = red[4] + red[5] + red[6] + red[7];
  const float mu = s * (1.f / 1024.f);
  const float rstd = rsqrtf(s2 * (1.f / 1024.f) - mu * mu + 1e-5f);
  const float4 gg = ((const float4*)g)[tid];
  const float4 bb = ((const float4*)b)[tid];
  u16x4 o4;
  o4[0] = f2bf((t.x - mu) * rstd * gg.x + bb.x);
  o4[1] = f2bf((t.y - mu) * rstd * gg.y + bb.y);
  o4[2] = f2bf((t.z - mu) * rstd * gg.z + bb.z);
  o4[3] = f2bf((t.w - mu) * rstd * gg.w + bb.w);
  ((u16x4*)(hb + base))[tid] = o4;
}

// ------- out += p[0..3] + b2 (MLP2 reduction over 4 bf16 partial slices) -------
__global__ __launch_bounds__(256)
void add4(float* __restrict__ out, const u16* __restrict__ p,
          const float* __restrict__ b2) {
  const int i = blockIdx.x * 256 + threadIdx.x;   // f4 index < 1048576
  const float4 o = ((const float4*)out)[i];
  const float4 bv = ((const float4*)b2)[i & 255];
  float a0 = o.x + bv.x, a1 = o.y + bv.y, a2 = o.z + bv.z, a3 = o.w + bv.w;
#pragma unroll
  for (int kz = 0; kz < 4; kz++) {
    const u16x4 h = ((const u16x4*)(p + (size_t)kz * 4194304))[i];
    a0 += bf2f(h[0]); a1 += bf2f(h[1]); a2 += bf2f(h[2]); a3 += bf2f(h[3]);
  }
  float4 r; r.x = a0; r.y = a1; r.z = a2; r.w = a3;
  ((float4*)out)[i] = r;
}

// ---------------- GEMM C = A * B^T, A[M,ldk] bf16, B[N,ldk] bf16 ----------------
// BM=256, BN=128, BK=64; 4 waves, wave tile 64x128 (acc 4x8). Proven 2-barrier
// structure. LDS rows 64 u16 (128B); m201-exact st_16x32 swizzle: stored 16B
// chunk c of row r holds global chunk c ^ (2*((r>>2)&1)) (bit1 ^= row-bit2),
// staged via pre-swizzled global src (dest wave-uniform linear, m104/m108);
// fragment reads at slot (quad ^ 2*((l16>>2)&1)) + kk*4  [measured conflict-
// free on this exact row geometry, learn_hip m201].
template <class Epi>
__global__ __launch_bounds__(256, 2)
void gemm_bt(const u16* __restrict__ A, const u16* __restrict__ Bw,
             int ldk, int K, int NB, Epi epi) {
  __shared__ __align__(16) u16 As[256 * 64];   // 32 KB
  __shared__ __align__(16) u16 Bs[128 * 64];   // 16 KB
  const int tid = threadIdx.x;
  const int wave = tid >> 6, lane = tid & 63;
  const int quad = lane >> 4, l16 = lane & 15;
  const int id = blockIdx.x;
  const int mb = id & 15;
  const int t = id >> 4;
  const int nb = t % NB;
  const int kz = t / NB;
  const int bm = mb * 256, bn = nb * 128;
  const int wm = wave * 64;

  const int srow = lane >> 3;                 // 0..7 (row within 8-row block)
  const int chunk = lane & 7;                 // 16B chunk slot this lane fills
  const int scol = (chunk ^ (2 * ((srow >> 2) & 1))) * 8;  // inverse-swizzled src
  // A: 8 staging instrs/thread (rows wave*64 + j*8 + srow)
  const u16* pa[8];
  u16* la[8];
#pragma unroll
  for (int j = 0; j < 8; j++) {
    pa[j] = A + (size_t)(bm + wave * 64 + j * 8 + srow) * ldk + (size_t)kz * K + scol;
    la[j] = &As[wave * 4096 + j * 512];       // wave-uniform dest
  }
  // B: 4 staging instrs/thread (rows wave*32 + j*8 + srow)
  const u16* pb[4];
  u16* lb[4];
#pragma unroll
  for (int j = 0; j < 4; j++) {
    pb[j] = Bw + (size_t)(bn + wave * 32 + j * 8 + srow) * ldk + (size_t)kz * K + scol;
    lb[j] = &Bs[wave * 2048 + j * 512];
  }

  const f32x4 fz = {0.f, 0.f, 0.f, 0.f};
  f32x4 acc[4][8];
#pragma unroll
  for (int i = 0; i < 4; i++)
#pragma unroll
    for (int j = 0; j < 8; j++) acc[i][j] = fz;

  const int qsw = (quad ^ (2 * ((l16 >> 2) & 1))) * 8;  // swizzled 16B slot

  for (int k0 = 0; k0 < K; k0 += 64) {
#pragma unroll
    for (int j = 0; j < 8; j++) { async_load16(pa[j], la[j]); pa[j] += 64; }
#pragma unroll
    for (int j = 0; j < 4; j++) { async_load16(pb[j], lb[j]); pb[j] += 64; }
    __syncthreads();
#pragma unroll
    for (int kk = 0; kk < 2; kk++) {
      const int slot = qsw + kk * 32;
      bf16x8 af[4], bfr[8];
#pragma unroll
      for (int mi = 0; mi < 4; mi++)
        af[mi] = *(const bf16x8*)&As[(wm + mi * 16 + l16) * 64 + slot];
#pragma unroll
      for (int ni = 0; ni < 8; ni++)
        bfr[ni] = *(const bf16x8*)&Bs[(ni * 16 + l16) * 64 + slot];
#pragma unroll
      for (int mi = 0; mi < 4; mi++)
#pragma unroll
        for (int ni = 0; ni < 8; ni++)
          acc[mi][ni] = __builtin_amdgcn_mfma_f32_16x16x32_bf16(af[mi], bfr[ni], acc[mi][ni], 0, 0, 0);
    }
    __syncthreads();
  }
#pragma unroll
  for (int mi = 0; mi < 4; mi++)
#pragma unroll
    for (int ni = 0; ni < 8; ni++)
      epi(bm + wm + mi * 16 + quad * 4, bn + ni * 16 + l16, kz, acc[mi][ni]);
}

// ---------------- epilogues (rows m0..m0+3, col n) ----------------
struct EpiQKV {   // q[b,h,s,e] scaled by 0.125*log2(e); k[b,h,s,e]; v^T[b,h,e,s]
  u16 *q, *k, *vt; const float *bq, *bk, *bv;
  __device__ void operator()(int m0, int n, int, f32x4 v) const {
    const int which = n >> 10, nn = n & 1023;
    const int hh = nn >> 6, e = nn & 63;
    const int bb = m0 >> 11, s0 = m0 & 2047;
    const size_t bh = (size_t)(bb * 16 + hh);
    if (which == 0) {
      const float bias = bq[nn];
      u16* p = &q[(bh * 2048 + s0) * 64 + e];
#pragma unroll
      for (int r = 0; r < 4; r++) p[r * 64] = bf_bits((v[r] + bias) * 0.18033688f);
    } else if (which == 1) {
      const float bias = bk[nn];
      u16* p = &k[(bh * 2048 + s0) * 64 + e];
#pragma unroll
      for (int r = 0; r < 4; r++) p[r * 64] = bf_bits(v[r] + bias);
    } else {
      const float bias = bv[nn];
      bf16x4 pk;
#pragma unroll
      for (int r = 0; r < 4; r++) pk[r] = (__bf16)(v[r] + bias);
      *(bf16x4*)&vt[(bh * 64 + e) * 2048 + s0] = pk;
    }
  }
};
struct EpiPartB {  // bf16 split-K partial -> p + kz*4194304  ([4096,1024] bf16)
  u16* p;
  __device__ void operator()(int m0, int n, int kz, f32x4 v) const {
    u16* pp = p + (size_t)kz * 4194304;
#pragma unroll
    for (int r = 0; r < 4; r++) pp[(size_t)(m0 + r) * 1024 + n] = bf_bits(v[r]);
  }
};
struct EpiGelu {  // gelu(u) = u * sigmoid(2*c*(u+0.044715u^3)) via exp2
  const float* b1; u16* o;
  __device__ void operator()(int m0, int n, int, f32x4 v) const {
    const float bias = b1[n];
#pragma unroll
    for (int r = 0; r < 4; r++) {
      const float u = v[r] + bias;
      const float z2 = u * (2.3021183f + 0.10294515f * u * u);
      const float d = 1.0f + exp2_fast(-z2);
      o[(size_t)(m0 + r) * 4096 + n] = bf_bits(u * rcp_fast(d));
    }
  }
};

// ---------------- flash attention, no-max softmax, KVBLK=128, 1 wave = 32 q-rows ----
// K LDS rows permuted (row u holds K[kv = 8*(u&15)+(u>>4)]) so the P tile lands
// in true-kv order as contiguous bf16x8 stores; V^T staged unpermuted.
__global__ __launch_bounds__(256)
void attn_kernel(const u16* __restrict__ Q, const u16* __restrict__ K,
                 const u16* __restrict__ Vt, u16* __restrict__ O) {
  __shared__ __align__(16) u16 Ks[128 * 72];    // 18.4 KB (K rows, 64 d + pad)
  __shared__ __align__(16) u16 Vs[64 * 136];    // 17.4 KB (e rows, 128 s + pad)
  __shared__ __align__(16) u16 Ps[4][32 * 136]; // 34.8 KB (per-wave P tiles)
  const int tid = threadIdx.x, wave = tid >> 6, lane = tid & 63;
  const int quad = lane >> 4, l16 = lane & 15;
  const int b = blockIdx.z, h = blockIdx.y, qt = blockIdx.x;
  const size_t bh = (size_t)(b * 16 + h);
  const u16* Qp = Q + bh * (size_t)(2048 * 64);
  const u16* Kp = K + bh * (size_t)(2048 * 64);
  const u16* Vp = Vt + bh * (size_t)(64 * 2048);
  const int q0 = qt * 128 + wave * 32;

  bf16x8 qf[2][2];
#pragma unroll
  for (int rg = 0; rg < 2; rg++) {
    const u16* qrow = &Qp[(size_t)(q0 + rg * 16 + l16) * 64 + quad * 8];
    qf[rg][0] = *(const bf16x8*)qrow;
    qf[rg][1] = *(const bf16x8*)(qrow + 32);
  }

  // K staging: 128 rows x 64 d / 256 thr = 32 u16/thr (half a row)
  const int srK = tid >> 1, scK = (tid & 1) * 32;
  const int krow = 8 * (srK & 15) + (srK >> 4);        // permuted key row
  const u16* kg = &Kp[(size_t)krow * 64 + scK];
  u16* kl = &Ks[srK * 72 + scK];
  // V staging: 64 e-rows x 128 s / 256 thr = 32 u16/thr
  const int srV = tid >> 2, scV = (tid & 3) * 32;
  const u16* vg = &Vp[(size_t)srV * 2048 + scV];
  u16* vl = &Vs[srV * 136 + scV];
  u16* Pw = &Ps[wave][0];

  bf16x8 ones;
#pragma unroll
  for (int i = 0; i < 8; i++) ones[i] = (__bf16)1.0f;

  const f32x4 fz = {0.f, 0.f, 0.f, 0.f};
  f32x4 acc[2][4], lsum[2];
#pragma unroll
  for (int rg = 0; rg < 2; rg++) {
    lsum[rg] = fz;
#pragma unroll
    for (int g = 0; g < 4; g++) acc[rg][g] = fz;
  }

  bf16x8 pk[4], pv[4];
#pragma unroll
  for (int c = 0; c < 4; c++) {
    pk[c] = *(const bf16x8*)(kg + 8 * c);
    pv[c] = *(const bf16x8*)(vg + 8 * c);
  }

  for (int t0 = 0; t0 < 2048; t0 += 128) {
#pragma unroll
    for (int c = 0; c < 4; c++) {
      *(bf16x8*)(kl + 8 * c) = pk[c];
      *(bf16x8*)(vl + 8 * c) = pv[c];
    }
    __syncthreads();
    kg += 128 * 64; vg += 128;
#pragma unroll
    for (int c = 0; c < 4; c++) {        // over-reads 1 tile past end: lands in
      pk[c] = *(const bf16x8*)(kg + 8 * c);   // the next ws buffer, unused
      pv[c] = *(const bf16x8*)(vg + 8 * c);
    }

    // ---- QK^T, first half (kv tiles g 0..3) ----
    f32x4 s[2][4];
    __builtin_amdgcn_s_setprio(1);
#pragma unroll
    for (int g = 0; g < 4; g++) {
      const u16* kr = &Ks[(g * 16 + l16) * 72 + quad * 8];
      const bf16x8 kb0 = *(const bf16x8*)kr;
      const bf16x8 kb1 = *(const bf16x8*)(kr + 32);
#pragma unroll
      for (int rg = 0; rg < 2; rg++) {
        f32x4 z = __builtin_amdgcn_mfma_f32_16x16x32_bf16(qf[rg][0], kb0, fz, 0, 0, 0);
        s[rg][g] = __builtin_amdgcn_mfma_f32_16x16x32_bf16(qf[rg][1], kb1, z, 0, 0, 0);
      }
    }
    __builtin_amdgcn_s_setprio(0);
#pragma unroll
    for (int rg = 0; rg < 2; rg++)
#pragma unroll
      for (int r = 0; r < 4; r++) {
        f32x4 pf;
#pragma unroll
        for (int g = 0; g < 4; g++) pf[g] = exp2_fast(s[rg][g][r]);
        const bf16x4 pb = __builtin_convertvector(pf, bf16x4);
        *(bf16x4*)&Pw[(rg * 16 + quad * 4 + r) * 136 + 8 * l16] = pb;
      }
    // ---- QK^T, second half (kv tiles g 4..7) ----
    __builtin_amdgcn_s_setprio(1);
#pragma unroll
    for (int g = 0; g < 4; g++) {
      const u16* kr = &Ks[((g + 4) * 16 + l16) * 72 + quad * 8];
      const bf16x8 kb0 = *(const bf16x8*)kr;
      const bf16x8 kb1 = *(const bf16x8*)(kr + 32);
#pragma unroll
      for (int rg = 0; rg < 2; rg++) {
        f32x4 z = __builtin_amdgcn_mfma_f32_16x16x32_bf16(qf[rg][0], kb0, fz, 0, 0, 0);
        s[rg][g] = __builtin_amdgcn_mfma_f32_16x16x32_bf16(qf[rg][1], kb1, z, 0, 0, 0);
      }
    }
    __builtin_amdgcn_s_setprio(0);
#pragma unroll
    for (int rg = 0; rg < 2; rg++)
#pragma unroll
      for (int r = 0; r < 4; r++) {
        f32x4 pf;
#pragma unroll
        for (int g = 0; g < 4; g++) pf[g] = exp2_fast(s[rg][g][r]);
        const bf16x4 pb = __builtin_convertvector(pf, bf16x4);
        *(bf16x4*)&Pw[(rg * 16 + quad * 4 + r) * 136 + 8 * l16 + 4] = pb;
      }

    // ---- P readback (true kv order) + row-sum + PV ----
    bf16x8 pa[2][4];
#pragma unroll
    for (int rg = 0; rg < 2; rg++)
#pragma unroll
      for (int hh2 = 0; hh2 < 4; hh2++) {
        pa[rg][hh2] = *(const bf16x8*)&Pw[(rg * 16 + l16) * 136 + quad * 8 + hh2 * 32];
        lsum[rg] = __builtin_amdgcn_mfma_f32_16x16x32_bf16(pa[rg][hh2], ones, lsum[rg], 0, 0, 0);
      }
    __builtin_amdgcn_s_setprio(1);
#pragma unroll
    for (int g = 0; g < 4; g++) {
      const u16* vr = &Vs[(g * 16 + l16) * 136 + quad * 8];
#pragma unroll
      for (int hh2 = 0; hh2 < 4; hh2++) {
        const bf16x8 vb = *(const bf16x8*)(vr + hh2 * 32);
#pragma unroll
        for (int rg = 0; rg < 2; rg++)
          acc[rg][g] = __builtin_amdgcn_mfma_f32_16x16x32_bf16(pa[rg][hh2], vb, acc[rg][g], 0, 0, 0);
      }
    }
    __builtin_amdgcn_s_setprio(0);
    __syncthreads();
  }
#pragma unroll
  for (int rg = 0; rg < 2; rg++)
#pragma unroll
    for (int r = 0; r < 4; r++) {
      const float inv = rcp_fast(lsum[rg][r]);
      const int s_row = q0 + rg * 16 + quad * 4 + r;
      u16* op = (u16*)&O[((size_t)(b * 2048 + s_row)) * 1024 + h * 64 + l16];
#pragma unroll
      for (int g = 0; g < 4; g++) op[g * 16] = bf_bits(acc[rg][g][r] * inv);
    }
}

// ---------------- launch ----------------
extern "C" void kernel_launch(void* const* d_in, const int* in_sizes, int n_in,
                              void* d_out, int out_size, void* d_ws, size_t ws_size,
                              hipStream_t stream) {
  const float* x   = (const float*)d_in[0];
  const float* Wq  = (const float*)d_in[1];
  const float* bq  = (const float*)d_in[2];
  const float* Wk  = (const float*)d_in[3];
  const float* bk  = (const float*)d_in[4];
  const float* Wv  = (const float*)d_in[5];
  const float* bv  = (const float*)d_in[6];
  const float* Wo  = (const float*)d_in[7];
  const float* bo  = (const float*)d_in[8];
  const float* g1  = (const float*)d_in[9];
  const float* be1 = (const float*)d_in[10];
  const float* W1  = (const float*)d_in[11];
  const float* b1  = (const float*)d_in[12];
  const float* W2  = (const float*)d_in[13];
  const float* b2  = (const float*)d_in[14];
  const float* g2  = (const float*)d_in[15];
  const float* be2 = (const float*)d_in[16];
  float* out = (float*)d_out;

  char* w = (char*)d_ws;
  u16* wqkv = (u16*)w; w += (size_t)3072 * 1024 * 2;   // contiguous bf16 weights:
  u16* wob  = (u16*)w; w += (size_t)1024 * 1024 * 2;   //   wqkv|wob|w1b|w2b
  u16* w1b  = (u16*)w; w += (size_t)4096 * 1024 * 2;
  u16* w2b  = (u16*)w; w += (size_t)1024 * 4096 * 2;
  u16* hb   = (u16*)w; w += (size_t)4096 * 1024 * 2;
  u16* qb   = (u16*)w; w += (size_t)4096 * 1024 * 2;   // later: MLP2 partials (4x8MB
  u16* kb   = (u16*)w; w += (size_t)4096 * 1024 * 2;   //   bf16 spanning qb..atb)
  u16* vtb  = (u16*)w; w += (size_t)4096 * 1024 * 2;
  u16* atb  = (u16*)w; w += (size_t)4096 * 1024 * 2;
  u16* m1b  = (u16*)w; w += (size_t)4096 * 4096 * 2;   // O-proj partials first (2x8MB)

  u16* op_part = m1b;   // O-proj bf16 partials, dead before MLP1 writes m1b
  u16* ml_part = qb;    // MLP2 bf16 partials, qb..atb all dead after O-proj

  f2b_all<<<12288, 256, 0, stream>>>(Wq, Wk, Wv, Wo, W1, W2, wqkv);

  ln_kernel<<<4096, 256, 0, stream>>>(x, g1, be1, hb);
  // QKV: M=4096, N=3072, K=1024 -> grid 16*24 = 384
  gemm_bt<EpiQKV><<<384, 256, 0, stream>>>(hb, wqkv, 1024, 1024, 24,
      EpiQKV{qb, kb, vtb, bq, bk, bv});
  attn_kernel<<<dim3(16, 16, 2), 256, 0, stream>>>(qb, kb, vtb, atb);
  // O-proj: N=1024, K=1024 split 2 -> grid 16*8*2 = 256
  gemm_bt<EpiPartB><<<256, 256, 0, stream>>>(atb, wob, 1024, 512, 8,
      EpiPartB{op_part});
  ln_fuse<<<4096, 256, 0, stream>>>(x, op_part, bo, g2, be2, out, hb);
  // MLP1: N=4096, K=1024 -> grid 16*32 = 512
  gemm_bt<EpiGelu><<<512, 256, 0, stream>>>(hb, w1b, 1024, 1024, 32,
      EpiGelu{b1, m1b});
  // MLP2: N=1024, K=4096 split 4 -> grid 16*8*4 = 512
  gemm_bt<EpiPartB><<<512, 256, 0, stream>>>(m1b, w2b, 4096, 1024, 8,
      EpiPartB{ml_part});
  add4<<<4096, 256, 0, stream>>>(out, ml_part, b2);
}